// Round 5
// baseline (749.601 us; speedup 1.0000x reference)
//
#include <hip/hip_runtime.h>

#define B_ 32
#define N_ 4096
#define ENC_ 1024
#define DEC_ 512
#define ATT_ 512

typedef __attribute__((ext_vector_type(8))) short short8;
typedef __attribute__((ext_vector_type(4))) float f32x4;

// fp32 -> bf16 bits, round-to-nearest-even (finite inputs)
__device__ __forceinline__ short f2bf(float f) {
  union { float f; unsigned u; } x; x.f = f;
  unsigned r = (x.u + 0x7FFFu + ((x.u >> 16) & 1u)) >> 16;
  return (short)r;
}

// ---------------------------------------------------------------------------
// Kernel 1: (a) att2[b,a] = dh[b,:]@W_dec[:,a] + b_dec[a] + b_enc[a]
//           (b) W_enc fp32 -> bf16 in MFMA B-fragment order:
//               Wfrag[((c*32+t)*64+l)*8+j] = W_enc[t*32+(l>>4)*8+j][c*16+(l&15)]
// ---------------------------------------------------------------------------
extern "C" __global__ void __launch_bounds__(256) prep_kernel(
    const float* __restrict__ dh, const float* __restrict__ W_dec,
    const float* __restrict__ b_dec, const float* __restrict__ b_enc,
    const float* __restrict__ W_enc,
    float* __restrict__ att2, short* __restrict__ Wfrag)
{
  if (blockIdx.x < B_) {
    __shared__ float dhs[DEC_];
    int b = blockIdx.x;
    for (int i = threadIdx.x; i < DEC_; i += 256) dhs[i] = dh[b * DEC_ + i];
    __syncthreads();
    for (int a = threadIdx.x; a < ATT_; a += 256) {
      float s = b_dec[a] + b_enc[a];
      for (int k = 0; k < DEC_; ++k) s += dhs[k] * W_dec[k * ATT_ + a];
      att2[b * ATT_ + a] = s;
    }
  } else {
    int idx = (blockIdx.x - B_) * 256 + threadIdx.x;  // 0..65535 chunks of 8
    int l = idx & 63;          // lane
    int t = (idx >> 6) & 31;   // k-fragment (32 each of K=32)
    int c = idx >> 11;         // col-fragment (32 of 16 cols)
    int col = c * 16 + (l & 15);
    int kb = t * 32 + (l >> 4) * 8;
    short8 p;
#pragma unroll
    for (int j = 0; j < 8; ++j) p[j] = f2bf(W_enc[(kb + j) * ATT_ + col]);
    *(short8*)(Wfrag + ((long)idx << 3)) = p;
  }
}

// ---------------------------------------------------------------------------
// Kernel 2: fused  e[b,n] = sum_a relu( (enc@W_enc)[n,a] + att2[b,a] ) * w[a]
// BARRIER-FREE K-loop. Tile 64 rows x 512 cols, 8 waves each 64x64.
// A: per-lane fp32 fragment loads straight from enc (8 KB step-slice, L1-
//    shared across the block's 8 waves), converted in-reg to bf16 at use.
// B: per-lane short8 fragment loads from L2-resident fragment-ordered Wfrag.
// Pipeline: iter T issues loads for T+1 (in flight ~1 full iter), converts
// pA[CUR] (loaded at T-1), runs 16 MFMA. No LDS, no __syncthreads until
// the epilogue reduce. Latency hidden by ILP + 2 waves/SIMD co-schedule.
// ---------------------------------------------------------------------------
extern "C" __global__ void __launch_bounds__(512) gemm_e_kernel(
    const float* __restrict__ enc, const short* __restrict__ Wfrag,
    const float* __restrict__ att2, const float* __restrict__ w_full,
    float* __restrict__ e_out)
{
  __shared__ float e_red[64][8];

  const int tid = threadIdx.x;
  const int lane = tid & 63;
  const int w = tid >> 6;                 // wave 0..7 -> cols w*64..w*64+63
  const int blk = blockIdx.x;             // 2048 = 32 batches x 64 row-tiles
  const int b = blk >> 6;
  const int n0 = (blk & 63) * 64;

  // A fragment lane pointers: row = n0 + r*16 + (lane&15), k0 = (lane>>4)*8
  const float* afp[4];
#pragma unroll
  for (int r = 0; r < 4; ++r)
    afp[r] = enc + (long)(b * N_ + n0 + r * 16 + (lane & 15)) * ENC_ +
             ((lane >> 4) * 8);

  // B fragments: frag(c,t) at Wfrag[(c*32+t)*512 + lane*8], c = w*4+cc
  const short* bptr = Wfrag + (long)(w * 4) * 16384 + lane * 8;

  f32x4 acc[4][4] = {};
  f32x4 pA[2][8];     // [buf][2r..2r+1] fp32 A fragments in flight
  short8 bfg[2][4];   // [buf][cc]

  // ---- prologue: load t=0 into buf 0
#pragma unroll
  for (int r = 0; r < 4; ++r) {
    pA[0][2 * r] = *(const f32x4*)(afp[r]);
    pA[0][2 * r + 1] = *(const f32x4*)(afp[r] + 4);
  }
#pragma unroll
  for (int cc = 0; cc < 4; ++cc)
    bfg[0][cc] = *(const short8*)(bptr + cc * 16384);

#define GBODY(CUR, NXT, T)                                                    \
  {                                                                           \
    if ((T) + 1 < 32) {                                                       \
      _Pragma("unroll")                                                       \
      for (int r = 0; r < 4; ++r) {                                           \
        pA[NXT][2 * r] = *(const f32x4*)(afp[r] + ((T) + 1) * 32);            \
        pA[NXT][2 * r + 1] = *(const f32x4*)(afp[r] + ((T) + 1) * 32 + 4);    \
      }                                                                       \
      _Pragma("unroll")                                                       \
      for (int cc = 0; cc < 4; ++cc)                                          \
        bfg[NXT][cc] =                                                        \
            *(const short8*)(bptr + cc * 16384 + ((T) + 1) * 512);            \
    }                                                                         \
    short8 afb[4];                                                            \
    _Pragma("unroll")                                                         \
    for (int r = 0; r < 4; ++r) {                                             \
      _Pragma("unroll")                                                       \
      for (int j = 0; j < 4; ++j) {                                           \
        afb[r][j] = f2bf(pA[CUR][2 * r][j]);                                  \
        afb[r][j + 4] = f2bf(pA[CUR][2 * r + 1][j]);                          \
      }                                                                       \
    }                                                                         \
    _Pragma("unroll")                                                         \
    for (int cc = 0; cc < 4; ++cc) {                                          \
      _Pragma("unroll")                                                       \
      for (int r = 0; r < 4; ++r)                                             \
        acc[r][cc] = __builtin_amdgcn_mfma_f32_16x16x32_bf16(                 \
            afb[r], bfg[CUR][cc], acc[r][cc], 0, 0, 0);                       \
    }                                                                         \
  }

  for (int tt = 0; tt < 32; tt += 2) {
    GBODY(0, 1, tt);
    GBODY(1, 0, tt + 1);
  }
#undef GBODY

  // ---- epilogue: e = sum_cols relu(att1 + att2) * w
  const int lq = lane >> 4, lr = lane & 15;
  float at2v[4], wv[4];
#pragma unroll
  for (int c = 0; c < 4; ++c) {
    int col = w * 64 + c * 16 + lr;
    at2v[c] = att2[b * ATT_ + col];
    wv[c] = w_full[col];
  }
#pragma unroll
  for (int r = 0; r < 4; ++r) {
#pragma unroll
    for (int j = 0; j < 4; ++j) {
      float s = 0.f;
#pragma unroll
      for (int c = 0; c < 4; ++c)
        s += fmaxf(acc[r][c][j] + at2v[c], 0.f) * wv[c];
      s += __shfl_xor(s, 1); s += __shfl_xor(s, 2);
      s += __shfl_xor(s, 4); s += __shfl_xor(s, 8);
      if (lr == 0) e_red[r * 16 + lq * 4 + j][w] = s;
    }
  }
  __syncthreads();
  if (tid < 64) {
    float ev = 0.f;
#pragma unroll
    for (int ww = 0; ww < 8; ++ww) ev += e_red[tid][ww];
    e_out[b * N_ + n0 + tid] = ev;
  }
}

// ---------------------------------------------------------------------------
// Kernel 3: softmax over N per batch. 32 blocks x 256 threads x 16 elems.
// ---------------------------------------------------------------------------
extern "C" __global__ void __launch_bounds__(256) softmax_kernel(
    const float* __restrict__ e, float* __restrict__ alpha)
{
  int b = blockIdx.x, tid = threadIdx.x;
  float v[16];
  float m = -1e30f;
#pragma unroll
  for (int i = 0; i < 16; ++i) {
    v[i] = e[b * N_ + i * 256 + tid];
    m = fmaxf(m, v[i]);
  }
  for (int off = 1; off < 64; off <<= 1) m = fmaxf(m, __shfl_xor(m, off));
  __shared__ float redm[4];
  if ((tid & 63) == 0) redm[tid >> 6] = m;
  __syncthreads();
  m = fmaxf(fmaxf(redm[0], redm[1]), fmaxf(redm[2], redm[3]));
  float s = 0.f;
#pragma unroll
  for (int i = 0; i < 16; ++i) { v[i] = expf(v[i] - m); s += v[i]; }
  for (int off = 1; off < 64; off <<= 1) s += __shfl_xor(s, off);
  __shared__ float reds[4];
  if ((tid & 63) == 0) reds[tid >> 6] = s;
  __syncthreads();
  s = reds[0] + reds[1] + reds[2] + reds[3];
  float inv = 1.0f / s;
#pragma unroll
  for (int i = 0; i < 16; ++i) alpha[b * N_ + i * 256 + tid] = v[i] * inv;
}

// ---------------------------------------------------------------------------
// Kernel 4: partial awe. grid = b(32) x cchunk(4, 256 cols) x nchunk(16, 256 n)
// ---------------------------------------------------------------------------
extern "C" __global__ void __launch_bounds__(256) awe_part_kernel(
    const float* __restrict__ enc, const float* __restrict__ alpha,
    float* __restrict__ part)
{
  __shared__ float als[256];
  __shared__ f32x4 red[256];
  int bi = blockIdx.x;
  int b = bi & 31, cchunk = (bi >> 5) & 3, nchunk = bi >> 7;
  int t = threadIdx.x;
  int n0 = nchunk * 256;
  als[t] = alpha[b * N_ + n0 + t];
  __syncthreads();
  int tcol = t & 63, tn = t >> 6;
  const float* base = enc + (long)b * N_ * ENC_ + (long)n0 * ENC_ +
                      cchunk * 256 + tcol * 4;
  f32x4 acc = {};
  for (int i = tn; i < 256; i += 4) {
    f32x4 vv = *(const f32x4*)(base + (long)i * ENC_);
    acc += als[i] * vv;
  }
  red[t] = acc;
  __syncthreads();
  if (t < 64) {
    f32x4 s = red[t] + red[t + 64] + red[t + 128] + red[t + 192];
    *(f32x4*)(&part[(long)nchunk * 32768 + b * 1024 + cchunk * 256 + t * 4]) = s;
  }
}

// Kernel 5: combine the 16 n-partials
extern "C" __global__ void __launch_bounds__(256) awe_reduce_kernel(
    const float* __restrict__ part, float* __restrict__ awe)
{
  int i = blockIdx.x * 256 + threadIdx.x;   // 32768 = 32*1024
  float s = 0.f;
#pragma unroll
  for (int p = 0; p < 16; ++p) s += part[(long)p * 32768 + i];
  awe[i] = s;
}

// ---------------------------------------------------------------------------
extern "C" void kernel_launch(void* const* d_in, const int* in_sizes, int n_in,
                              void* d_out, int out_size, void* d_ws, size_t ws_size,
                              hipStream_t stream) {
  const float* enc    = (const float*)d_in[0];
  const float* dh     = (const float*)d_in[1];
  const float* W_enc  = (const float*)d_in[2];
  const float* b_enc  = (const float*)d_in[3];
  const float* W_dec  = (const float*)d_in[4];
  const float* b_dec  = (const float*)d_in[5];
  const float* w_full = (const float*)d_in[6];
  // d_in[7] = b_full: softmax shift-invariant, unused.
  float* out = (float*)d_out;   // [awe 32*1024 | alpha 32*4096]

  char* ws = (char*)d_ws;
  float* att2  = (float*)ws;                                  // 64 KB
  short* Wfrag = (short*)(ws + 65536);                        // 1 MB
  float* e_buf = (float*)(ws + 65536 + 1048576);              // 512 KB
  float* part  = (float*)(ws + 65536 + 1048576 + 524288);     // 2 MB

  hipLaunchKernelGGL(prep_kernel, dim3(B_ + 256), dim3(256), 0, stream,
                     dh, W_dec, b_dec, b_enc, W_enc, att2, Wfrag);
  hipLaunchKernelGGL(gemm_e_kernel, dim3(2048), dim3(512), 0, stream,
                     enc, Wfrag, att2, w_full, e_buf);
  hipLaunchKernelGGL(softmax_kernel, dim3(B_), dim3(256), 0, stream,
                     e_buf, out + B_ * ENC_);
  hipLaunchKernelGGL(awe_part_kernel, dim3(2048), dim3(256), 0, stream,
                     enc, out + B_ * ENC_, part);
  hipLaunchKernelGGL(awe_reduce_kernel, dim3(128), dim3(256), 0, stream,
                     part, out);
}

// Round 6
// 332.329 us; speedup vs baseline: 2.2556x; 2.2556x over previous
//
#include <hip/hip_runtime.h>

#define B_ 32
#define N_ 4096
#define ENC_ 1024
#define DEC_ 512
#define ATT_ 512

typedef __attribute__((ext_vector_type(8))) short short8;
typedef __attribute__((ext_vector_type(4))) float f32x4;

// fp32 -> bf16 bits, round-to-nearest-even (finite inputs)
__device__ __forceinline__ short f2bf(float f) {
  union { float f; unsigned u; } x; x.f = f;
  unsigned r = (x.u + 0x7FFFu + ((x.u >> 16) & 1u)) >> 16;
  return (short)r;
}

// LDS-only fence + raw barrier: ds ops drain (lgkmcnt), global loads stay
// IN FLIGHT across the barrier (no vmcnt(0) drain).
__device__ __forceinline__ void lds_barrier() {
  asm volatile("s_waitcnt lgkmcnt(0)" ::: "memory");
  __builtin_amdgcn_s_barrier();
  asm volatile("" ::: "memory");
}

// ---------------------------------------------------------------------------
// Kernel 1: (a) att2[b,a] = dh[b,:]@W_dec[:,a] + b_dec[a] + b_enc[a]
//           (b) W_enc fp32 -> bf16 in MFMA B-fragment order:
//               Wfrag[((c*32+g)*64+l)*8+j] = W_enc[g*32+(l>>4)*8+j][c*16+(l&15)]
// ---------------------------------------------------------------------------
extern "C" __global__ void __launch_bounds__(256) prep_kernel(
    const float* __restrict__ dh, const float* __restrict__ W_dec,
    const float* __restrict__ b_dec, const float* __restrict__ b_enc,
    const float* __restrict__ W_enc,
    float* __restrict__ att2, short* __restrict__ Wfrag)
{
  if (blockIdx.x < B_) {
    __shared__ float dhs[DEC_];
    int b = blockIdx.x;
    for (int i = threadIdx.x; i < DEC_; i += 256) dhs[i] = dh[b * DEC_ + i];
    __syncthreads();
    for (int a = threadIdx.x; a < ATT_; a += 256) {
      float s = b_dec[a] + b_enc[a];
      for (int k = 0; k < DEC_; ++k) s += dhs[k] * W_dec[k * ATT_ + a];
      att2[b * ATT_ + a] = s;
    }
  } else {
    int idx = (blockIdx.x - B_) * 256 + threadIdx.x;  // 0..65535 chunks of 8
    int l = idx & 63;          // lane
    int g = (idx >> 6) & 31;   // k-chunk (32 chunks of K=32)
    int c = idx >> 11;         // col-fragment (32 of 16 cols)
    int col = c * 16 + (l & 15);
    int kb = g * 32 + (l >> 4) * 8;
    short8 p;
#pragma unroll
    for (int j = 0; j < 8; ++j) p[j] = f2bf(W_enc[(kb + j) * ATT_ + col]);
    *(short8*)(Wfrag + ((long)idx << 3)) = p;
  }
}

// ---------------------------------------------------------------------------
// Kernel 2: fused  e[b,n] = sum_a relu( (enc@W_enc)[n,a] + att2[b,a] ) * w[a]
// Tile 64 rows x 512 cols, 8 waves each 64x64.  BK=128 -> only 8 K-steps /
// 8 barriers (amortize barrier+skew 4x vs BK=32).  Fully unrolled.
// A: reg-staged (4x dwordx4 issued at sub-step 0, in flight ~3 sub-steps),
//    f2bf -> 2x ds_write_b128 into bf16 [64][128] XOR-swizzled LDS (16KB x2),
//    lgkm-only barrier.
// B: flat 32-chunk register stream from L2-resident Wfrag, alternating
//    bfgA/bfgB, exactly 1 sub-step ahead; never touches LDS or barriers.
// Per sub-step: {prefetch next B, 4x ds_read_b128 A-frags, 16 MFMA}.
// ---------------------------------------------------------------------------
extern "C" __global__ void __launch_bounds__(512) gemm_e_kernel(
    const float* __restrict__ enc, const short* __restrict__ Wfrag,
    const float* __restrict__ att2, const float* __restrict__ w_full,
    float* __restrict__ e_out)
{
  __shared__ __align__(16) short As[2][64 * 128];   // 16 KB each, swizzled
  __shared__ float e_red[64][8];

  const int tid = threadIdx.x;
  const int lane = tid & 63;
  const int w = tid >> 6;                 // wave 0..7 -> cols w*64..w*64+63
  const int blk = blockIdx.x;             // 2048 = 32 batches x 64 row-tiles
  const int b = blk >> 6;
  const int n0 = (blk & 63) * 64;

  // A staging: thread -> (row = tid>>3, 16-float chunk kc = tid&7)
  const int arow = tid >> 3;
  const int akc = tid & 7;
  const float* aptr = enc + ((long)(b * N_ + n0 + arow)) * ENC_ + akc * 16;
  const int awb0 = (arow * 256 + akc * 32) ^ ((arow & 7) << 4);
  const int awb1 = (arow * 256 + akc * 32 + 16) ^ ((arow & 7) << 4);

  // A fragment read: row rr = r*16+(lane&15); byte(s) = Pb[r]+s*64 ^ mask[r]
  int Pb[4], amask[4];
#pragma unroll
  for (int r = 0; r < 4; ++r) {
    int rr = r * 16 + (lane & 15);
    Pb[r] = rr * 256 + (lane >> 4) * 16;
    amask[r] = (rr & 7) << 4;
  }

  // B fragments: chunk g (k=g*32), col c=w*4+cc at
  // Wfrag[(c*32+g)*512 + lane*8]
  const short* bptr = Wfrag + (long)(w * 4) * 16384 + lane * 8;

  f32x4 acc[4][4] = {};
  short8 bfgA[4], bfgB[4];
  f32x4 pA[4];

  // ---- prologue: stage A(step 0), load B chunk 0
  {
    f32x4 v0 = *(const f32x4*)(aptr);
    f32x4 v1 = *(const f32x4*)(aptr + 4);
    f32x4 v2 = *(const f32x4*)(aptr + 8);
    f32x4 v3 = *(const f32x4*)(aptr + 12);
    short8 q0, q1;
#pragma unroll
    for (int j = 0; j < 4; ++j) {
      q0[j] = f2bf(v0[j]); q0[j + 4] = f2bf(v1[j]);
      q1[j] = f2bf(v2[j]); q1[j + 4] = f2bf(v3[j]);
    }
    *(short8*)((char*)As[0] + awb0) = q0;
    *(short8*)((char*)As[0] + awb1) = q1;
  }
#pragma unroll
  for (int cc = 0; cc < 4; ++cc)
    bfgA[cc] = *(const short8*)(bptr + cc * 16384);
  lds_barrier();

  // ---- main K loop: 8 steps of BK=128, fully unrolled
#pragma unroll
  for (int t = 0; t < 8; ++t) {
    const int cur = t & 1;
    // issue A global prefetch for step t+1 (consumed at end of this step)
    if (t + 1 < 8) {
#pragma unroll
      for (int i = 0; i < 4; ++i)
        pA[i] = *(const f32x4*)(aptr + (t + 1) * 128 + i * 4);
    }
#pragma unroll
    for (int s = 0; s < 4; ++s) {
      const int g = t * 4 + s;
      // prefetch next B chunk into the other buffer
      if (g + 1 < 32) {
        if ((s & 1) == 0) {
#pragma unroll
          for (int cc = 0; cc < 4; ++cc)
            bfgB[cc] = *(const short8*)(bptr + cc * 16384 + (g + 1) * 512);
        } else {
#pragma unroll
          for (int cc = 0; cc < 4; ++cc)
            bfgA[cc] = *(const short8*)(bptr + cc * 16384 + (g + 1) * 512);
        }
      }
      short8 af[4];
#pragma unroll
      for (int r = 0; r < 4; ++r)
        af[r] = *(const short8*)((const char*)As[cur] +
                                 ((Pb[r] + s * 64) ^ amask[r]));
      __builtin_amdgcn_s_setprio(1);
#pragma unroll
      for (int cc = 0; cc < 4; ++cc) {
#pragma unroll
        for (int r = 0; r < 4; ++r)
          acc[r][cc] = __builtin_amdgcn_mfma_f32_16x16x32_bf16(
              af[r], ((s & 1) == 0) ? bfgA[cc] : bfgB[cc], acc[r][cc],
              0, 0, 0);
      }
      __builtin_amdgcn_s_setprio(0);
    }
    // convert + stage A(t+1) into the other buffer, then barrier
    if (t + 1 < 8) {
      short8 q0, q1;
#pragma unroll
      for (int j = 0; j < 4; ++j) {
        q0[j] = f2bf(pA[0][j]); q0[j + 4] = f2bf(pA[1][j]);
        q1[j] = f2bf(pA[2][j]); q1[j + 4] = f2bf(pA[3][j]);
      }
      *(short8*)((char*)As[cur ^ 1] + awb0) = q0;
      *(short8*)((char*)As[cur ^ 1] + awb1) = q1;
      lds_barrier();
    }
  }

  // ---- epilogue: e = sum_cols relu(att1 + att2) * w
  const int lq = lane >> 4, lr = lane & 15;
  float at2v[4], wv[4];
#pragma unroll
  for (int c = 0; c < 4; ++c) {
    int col = w * 64 + c * 16 + lr;
    at2v[c] = att2[b * ATT_ + col];
    wv[c] = w_full[col];
  }
#pragma unroll
  for (int r = 0; r < 4; ++r) {
#pragma unroll
    for (int j = 0; j < 4; ++j) {
      float s = 0.f;
#pragma unroll
      for (int c = 0; c < 4; ++c)
        s += fmaxf(acc[r][c][j] + at2v[c], 0.f) * wv[c];
      s += __shfl_xor(s, 1); s += __shfl_xor(s, 2);
      s += __shfl_xor(s, 4); s += __shfl_xor(s, 8);
      if (lr == 0) e_red[r * 16 + lq * 4 + j][w] = s;
    }
  }
  __syncthreads();
  if (tid < 64) {
    float ev = 0.f;
#pragma unroll
    for (int ww = 0; ww < 8; ++ww) ev += e_red[tid][ww];
    e_out[b * N_ + n0 + tid] = ev;
  }
}

// ---------------------------------------------------------------------------
// Kernel 3: softmax over N per batch. 32 blocks x 256 threads x 16 elems.
// ---------------------------------------------------------------------------
extern "C" __global__ void __launch_bounds__(256) softmax_kernel(
    const float* __restrict__ e, float* __restrict__ alpha)
{
  int b = blockIdx.x, tid = threadIdx.x;
  float v[16];
  float m = -1e30f;
#pragma unroll
  for (int i = 0; i < 16; ++i) {
    v[i] = e[b * N_ + i * 256 + tid];
    m = fmaxf(m, v[i]);
  }
  for (int off = 1; off < 64; off <<= 1) m = fmaxf(m, __shfl_xor(m, off));
  __shared__ float redm[4];
  if ((tid & 63) == 0) redm[tid >> 6] = m;
  __syncthreads();
  m = fmaxf(fmaxf(redm[0], redm[1]), fmaxf(redm[2], redm[3]));
  float s = 0.f;
#pragma unroll
  for (int i = 0; i < 16; ++i) { v[i] = expf(v[i] - m); s += v[i]; }
  for (int off = 1; off < 64; off <<= 1) s += __shfl_xor(s, off);
  __shared__ float reds[4];
  if ((tid & 63) == 0) reds[tid >> 6] = s;
  __syncthreads();
  s = reds[0] + reds[1] + reds[2] + reds[3];
  float inv = 1.0f / s;
#pragma unroll
  for (int i = 0; i < 16; ++i) alpha[b * N_ + i * 256 + tid] = v[i] * inv;
}

// ---------------------------------------------------------------------------
// Kernel 4: partial awe. grid = b(32) x cchunk(4, 256 cols) x nchunk(16, 256 n)
// ---------------------------------------------------------------------------
extern "C" __global__ void __launch_bounds__(256) awe_part_kernel(
    const float* __restrict__ enc, const float* __restrict__ alpha,
    float* __restrict__ part)
{
  __shared__ float als[256];
  __shared__ f32x4 red[256];
  int bi = blockIdx.x;
  int b = bi & 31, cchunk = (bi >> 5) & 3, nchunk = bi >> 7;
  int t = threadIdx.x;
  int n0 = nchunk * 256;
  als[t] = alpha[b * N_ + n0 + t];
  __syncthreads();
  int tcol = t & 63, tn = t >> 6;
  const float* base = enc + (long)b * N_ * ENC_ + (long)n0 * ENC_ +
                      cchunk * 256 + tcol * 4;
  f32x4 acc = {};
  for (int i = tn; i < 256; i += 4) {
    f32x4 vv = *(const f32x4*)(base + (long)i * ENC_);
    acc += als[i] * vv;
  }
  red[t] = acc;
  __syncthreads();
  if (t < 64) {
    f32x4 s = red[t] + red[t + 64] + red[t + 128] + red[t + 192];
    *(f32x4*)(&part[(long)nchunk * 32768 + b * 1024 + cchunk * 256 + t * 4]) = s;
  }
}

// Kernel 5: combine the 16 n-partials
extern "C" __global__ void __launch_bounds__(256) awe_reduce_kernel(
    const float* __restrict__ part, float* __restrict__ awe)
{
  int i = blockIdx.x * 256 + threadIdx.x;   // 32768 = 32*1024
  float s = 0.f;
#pragma unroll
  for (int p = 0; p < 16; ++p) s += part[(long)p * 32768 + i];
  awe[i] = s;
}

// ---------------------------------------------------------------------------
extern "C" void kernel_launch(void* const* d_in, const int* in_sizes, int n_in,
                              void* d_out, int out_size, void* d_ws, size_t ws_size,
                              hipStream_t stream) {
  const float* enc    = (const float*)d_in[0];
  const float* dh     = (const float*)d_in[1];
  const float* W_enc  = (const float*)d_in[2];
  const float* b_enc  = (const float*)d_in[3];
  const float* W_dec  = (const float*)d_in[4];
  const float* b_dec  = (const float*)d_in[5];
  const float* w_full = (const float*)d_in[6];
  // d_in[7] = b_full: softmax shift-invariant, unused.
  float* out = (float*)d_out;   // [awe 32*1024 | alpha 32*4096]

  char* ws = (char*)d_ws;
  float* att2  = (float*)ws;                                  // 64 KB
  short* Wfrag = (short*)(ws + 65536);                        // 1 MB
  float* e_buf = (float*)(ws + 65536 + 1048576);              // 512 KB
  float* part  = (float*)(ws + 65536 + 1048576 + 524288);     // 2 MB

  hipLaunchKernelGGL(prep_kernel, dim3(B_ + 256), dim3(256), 0, stream,
                     dh, W_dec, b_dec, b_enc, W_enc, att2, Wfrag);
  hipLaunchKernelGGL(gemm_e_kernel, dim3(2048), dim3(512), 0, stream,
                     enc, Wfrag, att2, w_full, e_buf);
  hipLaunchKernelGGL(softmax_kernel, dim3(B_), dim3(256), 0, stream,
                     e_buf, out + B_ * ENC_);
  hipLaunchKernelGGL(awe_part_kernel, dim3(2048), dim3(256), 0, stream,
                     enc, out + B_ * ENC_, part);
  hipLaunchKernelGGL(awe_reduce_kernel, dim3(128), dim3(256), 0, stream,
                     part, out);
}

// Round 7
// 328.162 us; speedup vs baseline: 2.2842x; 1.0127x over previous
//
#include <hip/hip_runtime.h>

#define B_ 32
#define N_ 4096
#define ENC_ 1024
#define DEC_ 512
#define ATT_ 512

typedef __attribute__((ext_vector_type(8))) short short8;
typedef __attribute__((ext_vector_type(4))) float f32x4;

// fp32 -> bf16 bits, round-to-nearest-even (finite inputs)
__device__ __forceinline__ short f2bf(float f) {
  union { float f; unsigned u; } x; x.f = f;
  unsigned r = (x.u + 0x7FFFu + ((x.u >> 16) & 1u)) >> 16;
  return (short)r;
}

// LDS-only fence + raw barrier: ds ops drain (lgkmcnt), global loads stay
// IN FLIGHT across the barrier (no vmcnt(0) drain).
__device__ __forceinline__ void lds_barrier() {
  asm volatile("s_waitcnt lgkmcnt(0)" ::: "memory");
  __builtin_amdgcn_s_barrier();
  asm volatile("" ::: "memory");
}

// ---------------------------------------------------------------------------
// Kernel 1: (a) att2[b,a] = dh[b,:]@W_dec[:,a] + b_dec[a] + b_enc[a]
//           (b) W_enc fp32 -> bf16 in MFMA B-fragment order:
//               Wfrag[((c*32+g)*64+l)*8+j] = W_enc[g*32+(l>>4)*8+j][c*16+(l&15)]
// ---------------------------------------------------------------------------
extern "C" __global__ void __launch_bounds__(256) prep_kernel(
    const float* __restrict__ dh, const float* __restrict__ W_dec,
    const float* __restrict__ b_dec, const float* __restrict__ b_enc,
    const float* __restrict__ W_enc,
    float* __restrict__ att2, short* __restrict__ Wfrag)
{
  if (blockIdx.x < B_) {
    __shared__ float dhs[DEC_];
    int b = blockIdx.x;
    for (int i = threadIdx.x; i < DEC_; i += 256) dhs[i] = dh[b * DEC_ + i];
    __syncthreads();
    for (int a = threadIdx.x; a < ATT_; a += 256) {
      float s = b_dec[a] + b_enc[a];
      for (int k = 0; k < DEC_; ++k) s += dhs[k] * W_dec[k * ATT_ + a];
      att2[b * ATT_ + a] = s;
    }
  } else {
    int idx = (blockIdx.x - B_) * 256 + threadIdx.x;  // 0..65535 chunks of 8
    int l = idx & 63;          // lane
    int g = (idx >> 6) & 31;   // k-chunk (32 chunks of K=32)
    int c = idx >> 11;         // col-fragment (32 of 16 cols)
    int col = c * 16 + (l & 15);
    int kb = g * 32 + (l >> 4) * 8;
    short8 p;
#pragma unroll
    for (int j = 0; j < 8; ++j) p[j] = f2bf(W_enc[(kb + j) * ATT_ + col]);
    *(short8*)(Wfrag + ((long)idx << 3)) = p;
  }
}

// ---------------------------------------------------------------------------
// Kernel 2: fused  e_part[h,b,n] = sum_{a in half h} relu(att1+att2)*w
// 256-THREAD BLOCKS (4 waves), per-wave 64x64, block tile 64 rows x 256 cols.
// Designed for 2-3 co-resident blocks/CU (independent barrier domains ->
// cross-block latency hiding, the m114/m97 mechanism).
// Col-half siblings (same A rows) are 8 apart in blockIdx -> same XCD under
// %8 round-robin -> second block's A-read hits L2.
// A: reg-staged fp32->bf16 -> XOR-swizzled LDS [64][64] bf16, dbuf, BK=64.
// B: register stream from L2-resident fragment-ordered Wfrag (no LDS).
// ---------------------------------------------------------------------------
extern "C" __global__ void __launch_bounds__(256, 2) gemm_e_kernel(
    const float* __restrict__ enc, const short* __restrict__ Wfrag,
    const float* __restrict__ att2, const float* __restrict__ w_full,
    float* __restrict__ e_part)
{
  __shared__ __align__(16) short As[2][64 * 64];   // 8 KB each, swizzled
  __shared__ float e_red[64][4];

  const int tid = threadIdx.x;
  const int lane = tid & 63;
  const int w = tid >> 6;          // wave 0..3 -> cols h*256 + w*64 ..
  const int blk = blockIdx.x;      // 4096 = 256 groups x {h=0:8 pairs, h=1:8}
  const int g16 = blk >> 4;
  const int h = (blk >> 3) & 1;    // column half (0: cols 0-255, 1: 256-511)
  const int p = g16 * 8 + (blk & 7);   // pair id 0..2047 (b, rowtile)
  const int b = p >> 6;
  const int n0 = (p & 63) * 64;

  // A staging: thread -> (row = tid>>2, 16-float chunk kc = tid&3)
  const int arow = tid >> 2;
  const int akc = tid & 3;
  const float* aptr = enc + ((long)(b * N_ + n0 + arow)) * ENC_ + akc * 16;
  const int awb0 = (arow * 128 + akc * 32) ^ ((arow & 7) << 4);
  const int awb1 = (arow * 128 + akc * 32 + 16) ^ ((arow & 7) << 4);

  // A fragment reads: row rr = r*16+(lane&15), k-half s
  int arbyte[4][2];
#pragma unroll
  for (int r = 0; r < 4; ++r) {
    int rr = r * 16 + (lane & 15);
#pragma unroll
    for (int s = 0; s < 2; ++s)
      arbyte[r][s] =
          (rr * 128 + (lane >> 4) * 16 + s * 64) ^ ((rr & 7) << 4);
  }

  // B fragments: col-frag cf = h*16 + w*4 + cc, chunk g at
  // Wfrag[(cf*32+g)*512 + lane*8]
  const short* bptr = Wfrag + (long)(h * 16 + w * 4) * 16384 + lane * 8;

  f32x4 acc[4][4] = {};
  short8 bfgA[4], bfgB[4];
  f32x4 pA[4];

  // ---- prologue: stage A(step 0) direct, load B chunk 0
  {
    f32x4 v0 = *(const f32x4*)(aptr);
    f32x4 v1 = *(const f32x4*)(aptr + 4);
    f32x4 v2 = *(const f32x4*)(aptr + 8);
    f32x4 v3 = *(const f32x4*)(aptr + 12);
    short8 q0, q1;
#pragma unroll
    for (int j = 0; j < 4; ++j) {
      q0[j] = f2bf(v0[j]); q0[j + 4] = f2bf(v1[j]);
      q1[j] = f2bf(v2[j]); q1[j + 4] = f2bf(v3[j]);
    }
    *(short8*)((char*)As[0] + awb0) = q0;
    *(short8*)((char*)As[0] + awb1) = q1;
  }
#pragma unroll
  for (int cc = 0; cc < 4; ++cc)
    bfgA[cc] = *(const short8*)(bptr + cc * 16384);
  lds_barrier();

  // ---- main K loop: 16 steps of BK=64 (2 sub-steps of K=32 each)
#pragma unroll
  for (int t = 0; t < 16; ++t) {
    const int cur = t & 1;
    // A global prefetch for step t+1 (in flight across this whole step)
    if (t + 1 < 16) {
#pragma unroll
      for (int i = 0; i < 4; ++i)
        pA[i] = *(const f32x4*)(aptr + (t + 1) * 64 + i * 4);
    }
    // ---- sub-step 0: chunk 2t (bfgA); prefetch chunk 2t+1 -> bfgB
    {
#pragma unroll
      for (int cc = 0; cc < 4; ++cc)
        bfgB[cc] = *(const short8*)(bptr + cc * 16384 + (2 * t + 1) * 512);
      short8 af[4];
#pragma unroll
      for (int r = 0; r < 4; ++r)
        af[r] = *(const short8*)((const char*)As[cur] + arbyte[r][0]);
      __builtin_amdgcn_s_setprio(1);
#pragma unroll
      for (int cc = 0; cc < 4; ++cc)
#pragma unroll
        for (int r = 0; r < 4; ++r)
          acc[r][cc] = __builtin_amdgcn_mfma_f32_16x16x32_bf16(
              af[r], bfgA[cc], acc[r][cc], 0, 0, 0);
      __builtin_amdgcn_s_setprio(0);
    }
    // ---- sub-step 1: chunk 2t+1 (bfgB); prefetch chunk 2t+2 -> bfgA
    {
      if (2 * t + 2 < 32) {
#pragma unroll
        for (int cc = 0; cc < 4; ++cc)
          bfgA[cc] = *(const short8*)(bptr + cc * 16384 + (2 * t + 2) * 512);
      }
      short8 af[4];
#pragma unroll
      for (int r = 0; r < 4; ++r)
        af[r] = *(const short8*)((const char*)As[cur] + arbyte[r][1]);
      __builtin_amdgcn_s_setprio(1);
#pragma unroll
      for (int cc = 0; cc < 4; ++cc)
#pragma unroll
        for (int r = 0; r < 4; ++r)
          acc[r][cc] = __builtin_amdgcn_mfma_f32_16x16x32_bf16(
              af[r], bfgB[cc], acc[r][cc], 0, 0, 0);
      __builtin_amdgcn_s_setprio(0);
    }
    // ---- stage A(t+1), barrier
    if (t + 1 < 16) {
      short8 q0, q1;
#pragma unroll
      for (int j = 0; j < 4; ++j) {
        q0[j] = f2bf(pA[0][j]); q0[j + 4] = f2bf(pA[1][j]);
        q1[j] = f2bf(pA[2][j]); q1[j + 4] = f2bf(pA[3][j]);
      }
      *(short8*)((char*)As[cur ^ 1] + awb0) = q0;
      *(short8*)((char*)As[cur ^ 1] + awb1) = q1;
      lds_barrier();
    }
  }

  // ---- epilogue: partial e over this block's 256 cols
  const int lq = lane >> 4, lr = lane & 15;
  float at2v[4], wv[4];
#pragma unroll
  for (int c = 0; c < 4; ++c) {
    int col = h * 256 + w * 64 + c * 16 + lr;
    at2v[c] = att2[b * ATT_ + col];
    wv[c] = w_full[col];
  }
#pragma unroll
  for (int r = 0; r < 4; ++r) {
#pragma unroll
    for (int j = 0; j < 4; ++j) {
      float s = 0.f;
#pragma unroll
      for (int c = 0; c < 4; ++c)
        s += fmaxf(acc[r][c][j] + at2v[c], 0.f) * wv[c];
      s += __shfl_xor(s, 1); s += __shfl_xor(s, 2);
      s += __shfl_xor(s, 4); s += __shfl_xor(s, 8);
      if (lr == 0) e_red[r * 16 + lq * 4 + j][w] = s;
    }
  }
  __syncthreads();
  if (tid < 64) {
    float ev = e_red[tid][0] + e_red[tid][1] + e_red[tid][2] + e_red[tid][3];
    e_part[(long)h * (B_ * N_) + b * N_ + n0 + tid] = ev;
  }
}

// ---------------------------------------------------------------------------
// Kernel 3: softmax over N per batch, summing the two column-half partials.
// ---------------------------------------------------------------------------
extern "C" __global__ void __launch_bounds__(256) softmax_kernel(
    const float* __restrict__ e, float* __restrict__ alpha)
{
  int b = blockIdx.x, tid = threadIdx.x;
  float v[16];
  float m = -1e30f;
#pragma unroll
  for (int i = 0; i < 16; ++i) {
    int idx = b * N_ + i * 256 + tid;
    v[i] = e[idx] + e[B_ * N_ + idx];
    m = fmaxf(m, v[i]);
  }
  for (int off = 1; off < 64; off <<= 1) m = fmaxf(m, __shfl_xor(m, off));
  __shared__ float redm[4];
  if ((tid & 63) == 0) redm[tid >> 6] = m;
  __syncthreads();
  m = fmaxf(fmaxf(redm[0], redm[1]), fmaxf(redm[2], redm[3]));
  float s = 0.f;
#pragma unroll
  for (int i = 0; i < 16; ++i) { v[i] = expf(v[i] - m); s += v[i]; }
  for (int off = 1; off < 64; off <<= 1) s += __shfl_xor(s, off);
  __shared__ float reds[4];
  if ((tid & 63) == 0) reds[tid >> 6] = s;
  __syncthreads();
  s = reds[0] + reds[1] + reds[2] + reds[3];
  float inv = 1.0f / s;
#pragma unroll
  for (int i = 0; i < 16; ++i) alpha[b * N_ + i * 256 + tid] = v[i] * inv;
}

// ---------------------------------------------------------------------------
// Kernel 4: partial awe. grid = b(32) x cchunk(4, 256 cols) x nchunk(16, 256 n)
// ---------------------------------------------------------------------------
extern "C" __global__ void __launch_bounds__(256) awe_part_kernel(
    const float* __restrict__ enc, const float* __restrict__ alpha,
    float* __restrict__ part)
{
  __shared__ float als[256];
  __shared__ f32x4 red[256];
  int bi = blockIdx.x;
  int b = bi & 31, cchunk = (bi >> 5) & 3, nchunk = bi >> 7;
  int t = threadIdx.x;
  int n0 = nchunk * 256;
  als[t] = alpha[b * N_ + n0 + t];
  __syncthreads();
  int tcol = t & 63, tn = t >> 6;
  const float* base = enc + (long)b * N_ * ENC_ + (long)n0 * ENC_ +
                      cchunk * 256 + tcol * 4;
  f32x4 acc = {};
  for (int i = tn; i < 256; i += 4) {
    f32x4 vv = *(const f32x4*)(base + (long)i * ENC_);
    acc += als[i] * vv;
  }
  red[t] = acc;
  __syncthreads();
  if (t < 64) {
    f32x4 s = red[t] + red[t + 64] + red[t + 128] + red[t + 192];
    *(f32x4*)(&part[(long)nchunk * 32768 + b * 1024 + cchunk * 256 + t * 4]) = s;
  }
}

// Kernel 5: combine the 16 n-partials
extern "C" __global__ void __launch_bounds__(256) awe_reduce_kernel(
    const float* __restrict__ part, float* __restrict__ awe)
{
  int i = blockIdx.x * 256 + threadIdx.x;   // 32768 = 32*1024
  float s = 0.f;
#pragma unroll
  for (int p = 0; p < 16; ++p) s += part[(long)p * 32768 + i];
  awe[i] = s;
}

// ---------------------------------------------------------------------------
extern "C" void kernel_launch(void* const* d_in, const int* in_sizes, int n_in,
                              void* d_out, int out_size, void* d_ws, size_t ws_size,
                              hipStream_t stream) {
  const float* enc    = (const float*)d_in[0];
  const float* dh     = (const float*)d_in[1];
  const float* W_enc  = (const float*)d_in[2];
  const float* b_enc  = (const float*)d_in[3];
  const float* W_dec  = (const float*)d_in[4];
  const float* b_dec  = (const float*)d_in[5];
  const float* w_full = (const float*)d_in[6];
  // d_in[7] = b_full: softmax shift-invariant, unused.
  float* out = (float*)d_out;   // [awe 32*1024 | alpha 32*4096]

  char* ws = (char*)d_ws;
  float* att2  = (float*)ws;                                  // 64 KB
  short* Wfrag = (short*)(ws + 65536);                        // 1 MB
  float* e_buf = (float*)(ws + 65536 + 1048576);              // 1 MB (2 halves)
  float* part  = (float*)(ws + 65536 + 1048576 + 1048576);    // 2 MB

  hipLaunchKernelGGL(prep_kernel, dim3(B_ + 256), dim3(256), 0, stream,
                     dh, W_dec, b_dec, b_enc, W_enc, att2, Wfrag);
  hipLaunchKernelGGL(gemm_e_kernel, dim3(4096), dim3(256), 0, stream,
                     enc, Wfrag, att2, w_full, e_buf);
  hipLaunchKernelGGL(softmax_kernel, dim3(B_), dim3(256), 0, stream,
                     e_buf, out + B_ * ENC_);
  hipLaunchKernelGGL(awe_part_kernel, dim3(2048), dim3(256), 0, stream,
                     enc, out + B_ * ENC_, part);
  hipLaunchKernelGGL(awe_reduce_kernel, dim3(128), dim3(256), 0, stream,
                     part, out);
}